// Round 2
// baseline (1336.217 us; speedup 1.0000x reference)
//
#include <hip/hip_runtime.h>
#include <math.h>

#define NROWS 65536
#define KEMB  2048
#define DIM   64
#define DECAYF 0.99f
#define OMDF   0.01f
#define EPSF   1e-5f

// ---- ws layout (units of 4 bytes) ----
#define WS_DW    0         // 131072 floats (dw, fully written by k2b)
#define WS_CNT   131072    // 2048 uints   (counts, fully written by k2b)
#define WS_LOSS  133120    // 1 float      (zeroed by k0)
#define WS_ESQ   133632    // 2048 floats  (e_sq)
#define WS_SCALE 135680    // 2048 floats  (0.01/cs', K3->K4)
#define WS_IDX   137728    // 65536 ints   (argmin indices)

// ---- out layout (floats) ----
#define OUT_Q    0
#define OUT_ENC  4194304          // 65536*64
#define OUT_LOSS 138412032        // + 65536*2048
#define OUT_PERP 138412033
#define OUT_NE   138412034        // new_embedding (NOT 16B aligned -> float2 stores)
#define OUT_NCS  138543106        // + 2048*64

typedef float f32x4 __attribute__((ext_vector_type(4)));

// K0: precompute e_sq, zero loss accumulator
__global__ __launch_bounds__(256) void k0_prep(const float* __restrict__ E,
                                               float* __restrict__ ws) {
    int g = blockIdx.x * 256 + threadIdx.x;  // 8 blocks -> 2048 threads
    if (g == 0) ws[WS_LOSS] = 0.f;
    const float4* e4 = (const float4*)(E + (size_t)g * DIM);
    float s0 = 0.f, s1 = 0.f, s2 = 0.f, s3 = 0.f;
#pragma unroll
    for (int j = 0; j < 16; j++) {
        float4 v = e4[j];
        s0 = fmaf(v.x, v.x, s0); s1 = fmaf(v.y, v.y, s1);
        s2 = fmaf(v.z, v.z, s2); s3 = fmaf(v.w, v.w, s3);
    }
    ws[WS_ESQ + g] = (s0 + s1) + (s2 + s3);
}

// K1: argmin + quantized + loss + 512MB zero-fill. NO LDS in the hot loop:
// E rows are wave-uniform -> scalar (s_load) operands feeding v_fma directly.
// 1024 blocks x 256 threads; block owns 64 rows; thread group h = t>>6 scans
// codes [h*512, (h+1)*512) -> 16 waves/CU for latency hiding.
__global__ __launch_bounds__(256, 3) void k1_main(const float* __restrict__ x,
                                                  const float* __restrict__ E,
                                                  float* __restrict__ ws,
                                                  float* __restrict__ out) {
    const int t = threadIdx.x;
    const int b = blockIdx.x;
    const int l = t & 63;        // row within block
    const int h = t >> 6;        // k-quarter
    const int row = b * 64 + l;
    const float* __restrict__ esq = ws + WS_ESQ;

    f32x4* __restrict__ encz = (f32x4*)(out + OUT_ENC);
    const int g = b * 256 + t;   // zero-fill id in [0, 262144)

    // my row in registers
    float xr[64];
    {
        const float4* x4 = (const float4*)(x + (size_t)row * DIM);
#pragma unroll
        for (int j = 0; j < 16; j++) ((float4*)xr)[j] = x4[j];
    }
    float xs0 = 0.f, xs1 = 0.f, xs2 = 0.f, xs3 = 0.f;
#pragma unroll
    for (int j = 0; j < 16; j++) {
        xs0 = fmaf(xr[4 * j + 0], xr[4 * j + 0], xs0);
        xs1 = fmaf(xr[4 * j + 1], xr[4 * j + 1], xs1);
        xs2 = fmaf(xr[4 * j + 2], xr[4 * j + 2], xs2);
        xs3 = fmaf(xr[4 * j + 3], xr[4 * j + 3], xs3);
    }
    const float x_sq = (xs0 + xs1) + (xs2 + xs3);

    float best = 3.4e38f;
    int bidx = 0;
    const int kbase = h * 512;

    for (int kc = 0; kc < 4; kc++) {
        // zero-fill slice of encodings (stores drain under the FMA loop)
        {
            f32x4 z = (f32x4)(0.f);
#pragma unroll 8
            for (int j = 0; j < 32; j++)
                __builtin_nontemporal_store(z, encz + (size_t)(kc * 32 + j) * 262144 + g);
        }
        const int k0 = kbase + kc * 128;
        for (int k = k0; k < k0 + 128; k++) {
            const float4* e4 = (const float4*)(E + (size_t)k * DIM);  // uniform -> s_load
            float s0 = 0.f, s1 = 0.f, s2 = 0.f, s3 = 0.f;
#pragma unroll
            for (int j = 0; j < 16; j++) {
                float4 ev = e4[j];
                s0 = fmaf(xr[4 * j + 0], ev.x, s0);
                s1 = fmaf(xr[4 * j + 1], ev.y, s1);
                s2 = fmaf(xr[4 * j + 2], ev.z, s2);
                s3 = fmaf(xr[4 * j + 3], ev.w, s3);
            }
            float cr = (s0 + s1) + (s2 + s3);
            // reference rounding: (x_sq - 2*cross) + e_sq
            float dist = fmaf(-2.f, cr, x_sq) + esq[k];
            if (dist < best) { best = dist; bidx = k; }
        }
    }

    // combine the 4 k-quarters (ascending h + strict < keeps first-min tie rule)
    __shared__ float sf[256];
    __shared__ int si[256];
    sf[t] = best;
    si[t] = bidx;
    __syncthreads();
    if (t < 64) {
#pragma unroll
        for (int hh = 1; hh < 4; hh++) {
            float fb = sf[t + hh * 64];
            int ib = si[t + hh * 64];
            if (fb < best) { best = fb; bidx = ib; }
        }
        ((int*)ws)[WS_IDX + row] = bidx;

        // gather winning embedding, write quantized, accumulate loss
        const float4* ebb = (const float4*)(E + (size_t)bidx * DIM);
        float4* qo = (float4*)(out + OUT_Q + (size_t)row * DIM);
        float l0 = 0.f, l1 = 0.f, l2 = 0.f, l3 = 0.f;
#pragma unroll
        for (int j = 0; j < 16; j++) {
            float4 ev = ebb[j];
            qo[j] = ev;
            float d0 = ev.x - xr[4 * j + 0];
            float d1 = ev.y - xr[4 * j + 1];
            float d2 = ev.z - xr[4 * j + 2];
            float d3 = ev.w - xr[4 * j + 3];
            l0 = fmaf(d0, d0, l0); l1 = fmaf(d1, d1, l1);
            l2 = fmaf(d2, d2, l2); l3 = fmaf(d3, d3, l3);
        }
        float lsum = (l0 + l1) + (l2 + l3);
#pragma unroll
        for (int o = 32; o; o >>= 1) lsum += __shfl_down(lsum, o, 64);
        if (t == 0) unsafeAtomicAdd(ws + WS_LOSS, lsum);
    }
}

// K2: scatter the one-hot 1.0s
__global__ __launch_bounds__(256) void k2_ones(const int* __restrict__ idxp,
                                               float* __restrict__ out) {
    int n = blockIdx.x * 256 + threadIdx.x;  // 256 blocks
    out[OUT_ENC + (size_t)n * KEMB + idxp[n]] = 1.0f;
}

// K2b: dw + counts WITHOUT global atomics. 256 blocks; block b owns codes
// [8b, 8b+8). Scans the idx array, aggregates matching x rows in LDS.
__global__ __launch_bounds__(256) void k2b_dw(const int* __restrict__ idxp,
                                              const float* __restrict__ x,
                                              float* __restrict__ ws) {
    __shared__ float sdw[8][DIM];
    __shared__ unsigned int scnt[8];
    const int t = threadIdx.x;
    const int b = blockIdx.x;
    const int cbase = b * 8;

    sdw[t >> 6][t & 63] = 0.f;
    sdw[4 + (t >> 6)][t & 63] = 0.f;
    if (t < 8) scnt[t] = 0;
    __syncthreads();

    const int4* idx4 = (const int4*)idxp;
    for (int j = 0; j < 64; j++) {
        int4 v = idx4[t + j * 256];
        int rbase = 4 * (t + j * 256);
#pragma unroll
        for (int c = 0; c < 4; c++) {
            int cc = (&v.x)[c] - cbase;
            if (cc >= 0 && cc < 8) {
                atomicAdd(&scnt[cc], 1u);
                const float4* xr4 = (const float4*)(x + (size_t)(rbase + c) * DIM);
#pragma unroll
                for (int j2 = 0; j2 < 16; j2++) {
                    float4 xv = xr4[j2];
                    atomicAdd(&sdw[cc][4 * j2 + 0], xv.x);
                    atomicAdd(&sdw[cc][4 * j2 + 1], xv.y);
                    atomicAdd(&sdw[cc][4 * j2 + 2], xv.z);
                    atomicAdd(&sdw[cc][4 * j2 + 3], xv.w);
                }
            }
        }
    }
    __syncthreads();
    float* dwo = ws + WS_DW + (size_t)cbase * DIM;
    dwo[t] = (&sdw[0][0])[t];
    dwo[t + 256] = (&sdw[0][0])[t + 256];
    if (t < 8) ((unsigned int*)ws)[WS_CNT + cbase + t] = scnt[t];
}

// K3: cluster stats, loss, perplexity, scale for K4. One block of 256.
__global__ __launch_bounds__(256) void k3_stats(const float* __restrict__ cs_in,
                                                float* __restrict__ ws,
                                                float* __restrict__ out) {
    __shared__ float sred[8];
    __shared__ float s_n;
    int t = threadIdx.x;
    const unsigned int* cnt = ((const unsigned int*)ws) + WS_CNT;
    float* ncs_out = out + OUT_NCS;

    float ln = 0.f, lent = 0.f;
    float ncs_v[8];
#pragma unroll
    for (int j = 0; j < 8; j++) {
        int k = t + j * 256;
        float c = (float)cnt[k];
        float ncs = DECAYF * cs_in[k] + OMDF * c;
        ncs_out[k] = ncs;
        ncs_v[j] = ncs;
        ln += ncs;
        float p = c * (1.0f / 65536.0f);
        lent = fmaf(p, logf(p + 1e-10f), lent);
    }
#pragma unroll
    for (int o = 32; o; o >>= 1) {
        ln += __shfl_down(ln, o, 64);
        lent += __shfl_down(lent, o, 64);
    }
    if ((t & 63) == 0) { sred[t >> 6] = ln; sred[4 + (t >> 6)] = lent; }
    __syncthreads();
    if (t == 0) {
        float n = (sred[0] + sred[1]) + (sred[2] + sred[3]);
        float ent = (sred[4] + sred[5]) + (sred[6] + sred[7]);
        s_n = n;
        out[OUT_LOSS] = ws[WS_LOSS] * (1.0f / 4194304.0f);
        out[OUT_PERP] = expf(-ent);
    }
    __syncthreads();
    float n = s_n;
    float denom = n + (float)KEMB * EPSF;
#pragma unroll
    for (int j = 0; j < 8; j++) {
        int k = t + j * 256;
        float cs = (ncs_v[j] + EPSF) / denom * n;
        ws[WS_SCALE + k] = OMDF / cs;
    }
}

// K4: new_embedding = decay*E + dw * (0.01/cs). Output base not 16B aligned -> float2 stores.
__global__ __launch_bounds__(256) void k4_embed(const float* __restrict__ E,
                                                const float* __restrict__ ws,
                                                float* __restrict__ out) {
    int gq = blockIdx.x * 256 + threadIdx.x;  // 128 blocks -> 32768 float4-granules
    const float4* E4 = (const float4*)E;
    const float4* dw4 = (const float4*)(ws + WS_DW);
    float2* o2 = (float2*)(out + OUT_NE);
    int k = gq >> 4;
    float sc = ws[WS_SCALE + k];
    float4 e = E4[gq];
    float4 d = dw4[gq];
    float2 r0, r1;
    r0.x = fmaf(d.x, sc, DECAYF * e.x);
    r0.y = fmaf(d.y, sc, DECAYF * e.y);
    r1.x = fmaf(d.z, sc, DECAYF * e.z);
    r1.y = fmaf(d.w, sc, DECAYF * e.w);
    o2[2 * gq + 0] = r0;
    o2[2 * gq + 1] = r1;
}

extern "C" void kernel_launch(void* const* d_in, const int* in_sizes, int n_in,
                              void* d_out, int out_size, void* d_ws, size_t ws_size,
                              hipStream_t stream) {
    const float* x = (const float*)d_in[0];
    const float* E = (const float*)d_in[1];
    const float* cs = (const float*)d_in[2];
    float* out = (float*)d_out;
    float* ws = (float*)d_ws;

    hipLaunchKernelGGL(k0_prep, dim3(8), dim3(256), 0, stream, E, ws);
    hipLaunchKernelGGL(k1_main, dim3(1024), dim3(256), 0, stream, x, E, ws, out);
    hipLaunchKernelGGL(k2_ones, dim3(256), dim3(256), 0, stream,
                       ((const int*)ws) + WS_IDX, out);
    hipLaunchKernelGGL(k2b_dw, dim3(256), dim3(256), 0, stream,
                       ((const int*)ws) + WS_IDX, x, ws);
    hipLaunchKernelGGL(k3_stats, dim3(1), dim3(256), 0, stream, cs, ws, out);
    hipLaunchKernelGGL(k4_embed, dim3(128), dim3(256), 0, stream, E, ws, out);
}

// Round 3
// 485.727 us; speedup vs baseline: 2.7510x; 2.7510x over previous
//
#include <hip/hip_runtime.h>
#include <math.h>

#define NROWS 65536
#define KEMB  2048
#define DIM   64
#define DECAYF 0.99f
#define OMDF   0.01f
#define EPSF   1e-5f

// ---- ws layout (units of 4 bytes) ----
#define WS_DW    0         // 131072 floats (dw, fully written by k2b)
#define WS_CNT   131072    // 2048 uints   (counts, fully written by k2b)
#define WS_LOSS  133120    // 1 float      (zeroed by k0)
#define WS_ESQ   133632    // 2048 floats  (e_sq)
#define WS_SCALE 135680    // 2048 floats  (0.01/cs', K3->K4)
#define WS_IDX   137728    // 65536 ints   (argmin indices)

// ---- out layout (floats) ----
#define OUT_Q    0
#define OUT_ENC  4194304          // 65536*64
#define OUT_LOSS 138412032        // + 65536*2048
#define OUT_PERP 138412033
#define OUT_NE   138412034        // new_embedding; used as x_sq scratch k0->k1, overwritten by k4
#define OUT_NCS  138543106        // + 2048*64

typedef float f32x4 __attribute__((ext_vector_type(4)));

// K0: e_sq, x_sq (4-partial rounding, matches prior passing rounds), zero loss
__global__ __launch_bounds__(256) void k0_prep(const float* __restrict__ x,
                                               const float* __restrict__ E,
                                               float* __restrict__ ws,
                                               float* __restrict__ out) {
    int g = blockIdx.x * 256 + threadIdx.x;  // 256 blocks -> 65536 threads
    if (g == 0) ws[WS_LOSS] = 0.f;
    if (g < KEMB) {
        const float4* e4 = (const float4*)(E + (size_t)g * DIM);
        float s0 = 0.f, s1 = 0.f, s2 = 0.f, s3 = 0.f;
#pragma unroll
        for (int j = 0; j < 16; j++) {
            float4 v = e4[j];
            s0 = fmaf(v.x, v.x, s0); s1 = fmaf(v.y, v.y, s1);
            s2 = fmaf(v.z, v.z, s2); s3 = fmaf(v.w, v.w, s3);
        }
        ws[WS_ESQ + g] = (s0 + s1) + (s2 + s3);
    }
    {
        const float4* x4 = (const float4*)(x + (size_t)g * DIM);
        float s0 = 0.f, s1 = 0.f, s2 = 0.f, s3 = 0.f;
#pragma unroll
        for (int j = 0; j < 16; j++) {
            float4 v = x4[j];
            s0 = fmaf(v.x, v.x, s0); s1 = fmaf(v.y, v.y, s1);
            s2 = fmaf(v.z, v.z, s2); s3 = fmaf(v.w, v.w, s3);
        }
        out[OUT_NE + g] = (s0 + s1) + (s2 + s3);
    }
}

// K1: SGEMM-structured argmin. 512 blocks x 256 threads.
// Block: 128 rows x 2048 codes (16 passes of 128). Thread (tx=t&15, ty=t>>4)
// owns an 8x8 micro-tile: rows ty*8.., codes tx*8.. within the pass tile.
// LDS: xT[64][128] (staged once), eT[64][128 parity-split] (per pass).
__global__ __launch_bounds__(256, 2) void k1_main(const float* __restrict__ x,
                                                  const float* __restrict__ E,
                                                  float* __restrict__ ws,
                                                  float* __restrict__ out) {
    __shared__ float sxT[64 * 128];   // 32 KB
    __shared__ float seT[64 * 128];   // 32 KB; reused as int sIdx[128] at the end

    const int t = threadIdx.x;
    const int b = blockIdx.x;
    const int tx = t & 15;
    const int ty = t >> 4;

    // ---- stage xT (once). lanes r-fast: LDS writes conflict-free ----
    {
        const float4* x4 = (const float4*)x;
        const int r = t & 127;
        const int dchi = t >> 7;
#pragma unroll
        for (int i = 0; i < 8; i++) {
            int dc = dchi + 2 * i;
            float4 v = x4[((size_t)b * 128 + r) * 16 + dc];
            sxT[(4 * dc + 0) * 128 + r] = v.x;
            sxT[(4 * dc + 1) * 128 + r] = v.y;
            sxT[(4 * dc + 2) * 128 + r] = v.z;
            sxT[(4 * dc + 3) * 128 + r] = v.w;
        }
    }

    // x_sq for my 8 rows (scratch written by k0; offset is even -> float2 loads)
    float xsq[8];
    {
        const float2* xs2 = (const float2*)(out + OUT_NE + (size_t)b * 128 + ty * 8);
#pragma unroll
        for (int j = 0; j < 4; j++) {
            float2 v = xs2[j];
            xsq[2 * j] = v.x; xsq[2 * j + 1] = v.y;
        }
    }

    float best[8];
    int bidx[8];
#pragma unroll
    for (int rr = 0; rr < 8; rr++) { best[rr] = 3.4e38f; bidx[rr] = 0; }

    f32x4* __restrict__ encz = (f32x4*)(out + OUT_ENC);
    const int g = b * 256 + t;

    for (int pass = 0; pass < 16; pass++) {
        __syncthreads();
        // ---- stage eT with parity-split chunk layout: code-chunk kq (4 floats)
        // stored at float4-pos (kq&1)*16 + (kq>>1). Writes 2-way (free). ----
        {
            const float4* e4 = (const float4*)E;
            const int kl = t & 127;
            const int dchi = t >> 7;
            const int c = kl >> 2;
            const int fo = (((c & 1) << 4) + (c >> 1)) * 4 + (kl & 3);
#pragma unroll
            for (int i = 0; i < 8; i++) {
                int dc = dchi + 2 * i;
                float4 v = e4[((size_t)pass * 128 + kl) * 16 + dc];
                seT[(4 * dc + 0) * 128 + fo] = v.x;
                seT[(4 * dc + 1) * 128 + fo] = v.y;
                seT[(4 * dc + 2) * 128 + fo] = v.z;
                seT[(4 * dc + 3) * 128 + fo] = v.w;
            }
        }
        __syncthreads();

        // ---- zero-fill slice of encodings (drains under the FMA loop) ----
        {
            f32x4 z = (f32x4)(0.f);
#pragma unroll
            for (int j = 0; j < 16; j++)
                __builtin_nontemporal_store(z, encz + (size_t)(pass * 16 + j) * 131072 + g);
        }

        // ---- 8x8 outer-product accumulation over d ----
        float acc[8][8];
#pragma unroll
        for (int rr = 0; rr < 8; rr++)
#pragma unroll
            for (int cc = 0; cc < 8; cc++) acc[rr][cc] = 0.f;

        const float* xb  = sxT + ty * 8;
        const float* ebA = seT + tx * 4;        // codes tx*8+0..3 (chunk 2tx   -> pos tx)
        const float* ebB = seT + 64 + tx * 4;   // codes tx*8+4..7 (chunk 2tx+1 -> pos 16+tx)
#pragma unroll 2
        for (int d = 0; d < 64; d++) {
            f32x4 a0 = *(const f32x4*)(xb + d * 128);
            f32x4 a1 = *(const f32x4*)(xb + d * 128 + 4);
            f32x4 b0 = *(const f32x4*)(ebA + d * 128);
            f32x4 b1 = *(const f32x4*)(ebB + d * 128);
            float ar[8] = {a0.x, a0.y, a0.z, a0.w, a1.x, a1.y, a1.z, a1.w};
            float br[8] = {b0.x, b0.y, b0.z, b0.w, b1.x, b1.y, b1.z, b1.w};
#pragma unroll
            for (int rr = 0; rr < 8; rr++)
#pragma unroll
                for (int cc = 0; cc < 8; cc++)
                    acc[rr][cc] = fmaf(ar[rr], br[cc], acc[rr][cc]);
        }

        // ---- fold distances into running argmin (k ascending -> first-min rule) ----
        const float4* esq4 = (const float4*)(ws + WS_ESQ + pass * 128 + tx * 8);
        float4 eq0 = esq4[0], eq1 = esq4[1];
        float eq[8] = {eq0.x, eq0.y, eq0.z, eq0.w, eq1.x, eq1.y, eq1.z, eq1.w};
        const int kb = pass * 128 + tx * 8;
#pragma unroll
        for (int rr = 0; rr < 8; rr++)
#pragma unroll
            for (int cc = 0; cc < 8; cc++) {
                float dist = fmaf(-2.f, acc[rr][cc], xsq[rr]) + eq[cc];
                if (dist < best[rr]) { best[rr] = dist; bidx[rr] = kb + cc; }
            }
    }

    // ---- cross-tx reduce: xor butterfly over the 16 lanes sharing rows ----
    __syncthreads();                       // seT reads done; reuse as sIdx
    int* sIdx = (int*)seT;
#pragma unroll
    for (int rr = 0; rr < 8; rr++) {
        float bd = best[rr]; int bi = bidx[rr];
#pragma unroll
        for (int m = 1; m < 16; m <<= 1) {
            float od = __shfl_xor(bd, m, 64);
            int   oi = __shfl_xor(bi, m, 64);
            if (od < bd || (od == bd && oi < bi)) { bd = od; bi = oi; }
        }
        if (tx == 0) sIdx[ty * 8 + rr] = bi;
    }
    __syncthreads();

    // ---- tail: idx write, quantized gather, loss (2 full waves active) ----
    float lsum = 0.f;
    if (t < 128) {
        const int row = b * 128 + t;
        const int bi = sIdx[t];
        ((int*)ws)[WS_IDX + row] = bi;
        const float4* ebb = (const float4*)(E + (size_t)bi * DIM);
        const float4* xr4 = (const float4*)(x + (size_t)row * DIM);
        float4* qo = (float4*)(out + OUT_Q + (size_t)row * DIM);
        float l0 = 0.f, l1 = 0.f, l2 = 0.f, l3 = 0.f;
#pragma unroll
        for (int j = 0; j < 16; j++) {
            float4 ev = ebb[j];
            float4 xv = xr4[j];
            qo[j] = ev;
            float d0 = ev.x - xv.x, d1 = ev.y - xv.y;
            float d2 = ev.z - xv.z, d3 = ev.w - xv.w;
            l0 = fmaf(d0, d0, l0); l1 = fmaf(d1, d1, l1);
            l2 = fmaf(d2, d2, l2); l3 = fmaf(d3, d3, l3);
        }
        lsum = (l0 + l1) + (l2 + l3);
#pragma unroll
        for (int o = 32; o; o >>= 1) lsum += __shfl_down(lsum, o, 64);
        if ((t & 63) == 0) unsafeAtomicAdd(ws + WS_LOSS, lsum);
    }
}

// K2: scatter the one-hot 1.0s
__global__ __launch_bounds__(256) void k2_ones(const int* __restrict__ idxp,
                                               float* __restrict__ out) {
    int n = blockIdx.x * 256 + threadIdx.x;  // 256 blocks
    out[OUT_ENC + (size_t)n * KEMB + idxp[n]] = 1.0f;
}

// K2b: dw + counts without global atomics. 256 blocks; block b owns codes [8b, 8b+8).
__global__ __launch_bounds__(256) void k2b_dw(const int* __restrict__ idxp,
                                              const float* __restrict__ x,
                                              float* __restrict__ ws) {
    __shared__ float sdw[8][DIM];
    __shared__ unsigned int scnt[8];
    const int t = threadIdx.x;
    const int b = blockIdx.x;
    const int cbase = b * 8;

    sdw[t >> 6][t & 63] = 0.f;
    sdw[4 + (t >> 6)][t & 63] = 0.f;
    if (t < 8) scnt[t] = 0;
    __syncthreads();

    const int4* idx4 = (const int4*)idxp;
    for (int j = 0; j < 64; j++) {
        int4 v = idx4[t + j * 256];
        int rbase = 4 * (t + j * 256);
#pragma unroll
        for (int c = 0; c < 4; c++) {
            int cc = (&v.x)[c] - cbase;
            if (cc >= 0 && cc < 8) {
                atomicAdd(&scnt[cc], 1u);
                const float4* xr4 = (const float4*)(x + (size_t)(rbase + c) * DIM);
#pragma unroll
                for (int j2 = 0; j2 < 16; j2++) {
                    float4 xv = xr4[j2];
                    atomicAdd(&sdw[cc][4 * j2 + 0], xv.x);
                    atomicAdd(&sdw[cc][4 * j2 + 1], xv.y);
                    atomicAdd(&sdw[cc][4 * j2 + 2], xv.z);
                    atomicAdd(&sdw[cc][4 * j2 + 3], xv.w);
                }
            }
        }
    }
    __syncthreads();
    float* dwo = ws + WS_DW + (size_t)cbase * DIM;
    dwo[t] = (&sdw[0][0])[t];
    dwo[t + 256] = (&sdw[0][0])[t + 256];
    if (t < 8) ((unsigned int*)ws)[WS_CNT + cbase + t] = scnt[t];
}

// K3: cluster stats, loss, perplexity, scale for K4. One block of 256.
__global__ __launch_bounds__(256) void k3_stats(const float* __restrict__ cs_in,
                                                float* __restrict__ ws,
                                                float* __restrict__ out) {
    __shared__ float sred[8];
    __shared__ float s_n;
    int t = threadIdx.x;
    const unsigned int* cnt = ((const unsigned int*)ws) + WS_CNT;
    float* ncs_out = out + OUT_NCS;

    float ln = 0.f, lent = 0.f;
    float ncs_v[8];
#pragma unroll
    for (int j = 0; j < 8; j++) {
        int k = t + j * 256;
        float c = (float)cnt[k];
        float ncs = DECAYF * cs_in[k] + OMDF * c;
        ncs_out[k] = ncs;
        ncs_v[j] = ncs;
        ln += ncs;
        float p = c * (1.0f / 65536.0f);
        lent = fmaf(p, logf(p + 1e-10f), lent);
    }
#pragma unroll
    for (int o = 32; o; o >>= 1) {
        ln += __shfl_down(ln, o, 64);
        lent += __shfl_down(lent, o, 64);
    }
    if ((t & 63) == 0) { sred[t >> 6] = ln; sred[4 + (t >> 6)] = lent; }
    __syncthreads();
    if (t == 0) {
        float n = (sred[0] + sred[1]) + (sred[2] + sred[3]);
        float ent = (sred[4] + sred[5]) + (sred[6] + sred[7]);
        s_n = n;
        out[OUT_LOSS] = ws[WS_LOSS] * (1.0f / 4194304.0f);
        out[OUT_PERP] = expf(-ent);
    }
    __syncthreads();
    float n = s_n;
    float denom = n + (float)KEMB * EPSF;
#pragma unroll
    for (int j = 0; j < 8; j++) {
        int k = t + j * 256;
        float cs = (ncs_v[j] + EPSF) / denom * n;
        ws[WS_SCALE + k] = OMDF / cs;
    }
}

// K4: new_embedding = decay*E + dw * (0.01/cs). Overwrites the x_sq scratch.
__global__ __launch_bounds__(256) void k4_embed(const float* __restrict__ E,
                                                const float* __restrict__ ws,
                                                float* __restrict__ out) {
    int gq = blockIdx.x * 256 + threadIdx.x;  // 128 blocks -> 32768 float4-granules
    const float4* E4 = (const float4*)E;
    const float4* dw4 = (const float4*)(ws + WS_DW);
    float2* o2 = (float2*)(out + OUT_NE);
    int k = gq >> 4;
    float sc = ws[WS_SCALE + k];
    float4 e = E4[gq];
    float4 d = dw4[gq];
    float2 r0, r1;
    r0.x = fmaf(d.x, sc, DECAYF * e.x);
    r0.y = fmaf(d.y, sc, DECAYF * e.y);
    r1.x = fmaf(d.z, sc, DECAYF * e.z);
    r1.y = fmaf(d.w, sc, DECAYF * e.w);
    o2[2 * gq + 0] = r0;
    o2[2 * gq + 1] = r1;
}

extern "C" void kernel_launch(void* const* d_in, const int* in_sizes, int n_in,
                              void* d_out, int out_size, void* d_ws, size_t ws_size,
                              hipStream_t stream) {
    const float* x = (const float*)d_in[0];
    const float* E = (const float*)d_in[1];
    const float* cs = (const float*)d_in[2];
    float* out = (float*)d_out;
    float* ws = (float*)d_ws;

    hipLaunchKernelGGL(k0_prep, dim3(256), dim3(256), 0, stream, x, E, ws, out);
    hipLaunchKernelGGL(k1_main, dim3(512), dim3(256), 0, stream, x, E, ws, out);
    hipLaunchKernelGGL(k2_ones, dim3(256), dim3(256), 0, stream,
                       ((const int*)ws) + WS_IDX, out);
    hipLaunchKernelGGL(k2b_dw, dim3(256), dim3(256), 0, stream,
                       ((const int*)ws) + WS_IDX, x, ws);
    hipLaunchKernelGGL(k3_stats, dim3(1), dim3(256), 0, stream, cs, ws, out);
    hipLaunchKernelGGL(k4_embed, dim3(128), dim3(256), 0, stream, E, ws, out);
}